// Round 4
// baseline (874.347 us; speedup 1.0000x reference)
//
#include <hip/hip_runtime.h>
#include <cstdint>
#include <cstddef>

#define B_   8
#define N_   2048
#define D_   1024
#define DK_  256
#define M_   (B_ * N_)   // 16384
#define TOPK 32

typedef unsigned short ushort_t;
typedef float  fvec4 __attribute__((ext_vector_type(4)));
typedef short  bvec8 __attribute__((ext_vector_type(8)));   // 8 bf16 (bits)
typedef float  avec4 __attribute__((ext_vector_type(4)));   // f32 MFMA acc
typedef double dvec2 __attribute__((ext_vector_type(2)));   // 16B LDS chunk
typedef int    ivec4 __attribute__((ext_vector_type(4)));   // 16B staging

__device__ inline ushort_t f32_to_bf16_rn(float f) {
  unsigned u = __float_as_uint(f);
  u += 0x7fffu + ((u >> 16) & 1u);     // RNE (no inf/nan in this data)
  return (ushort_t)(u >> 16);
}

// --------------------------------------------------------------------------
// Kernel 1: fused Q/K projection GEMM, f64 accumulation on the VALU.
// Proven r2 indexing (tile 64m x 128j, BK=16, 4x8/thread); LDS now holds
// f64 so the inner loop is pure dfma (cvt happens once at staging).
// --------------------------------------------------------------------------
__global__ __launch_bounds__(256) void proj_kernel(
    const float* __restrict__ X, const float* __restrict__ Wq,
    const float* __restrict__ bq, const float* __restrict__ Wk,
    const float* __restrict__ bk, double* __restrict__ Qd,
    double* __restrict__ Kd, ushort_t* __restrict__ Qbf,
    ushort_t* __restrict__ Kbf)
{
  __shared__ double As[16][66];    // [k][m], pad 66 (row = 528B, 16B-aligned)
  __shared__ double Bs[16][132];   // [k][j], pad 132 (row = 1056B, 16B-aligned)
  const int tid = threadIdx.x;
  const int tx = tid & 15;         // 16 col-groups of 8
  const int ty = tid >> 4;         // 16 row-groups of 4
  const int m0 = blockIdx.y * 64;
  const int j0 = blockIdx.x * 128;          // 0,128,256,384
  const bool isQ = (j0 < 256);
  const float* Wp = isQ ? Wq : Wk;
  const float* bp = isQ ? bq : bk;
  const int jw = isQ ? j0 : (j0 - 256);

  double acc[4][8];
#pragma unroll
  for (int i = 0; i < 4; i++)
#pragma unroll
    for (int j = 0; j < 8; j++) acc[i][j] = 0.0;

  for (int k0 = 0; k0 < D_; k0 += 16) {
    {  // A tile: 64 rows x 16 k, transposed As[k][m]; cvt f32->f64 here
      const int kt = tid & 15, mt = tid >> 4;
#pragma unroll
      for (int p = 0; p < 4; p++) {
        const int m = mt + 16 * p;
        As[kt][m] = (double)X[(size_t)(m0 + m) * D_ + k0 + kt];
      }
    }
    {  // B tile: 16 k x 128 j; fvec4 load, cvt, 2x dvec2 (16B) stores
      const int c4 = tid & 31, kt = tid >> 5;
#pragma unroll
      for (int p = 0; p < 2; p++) {
        const int k = kt + 8 * p;
        const fvec4 v = *(const fvec4*)&Wp[(size_t)(k0 + k) * DK_ + jw + c4 * 4];
        dvec2 lo, hi;
        lo[0] = (double)v[0]; lo[1] = (double)v[1];
        hi[0] = (double)v[2]; hi[1] = (double)v[3];
        *(dvec2*)&Bs[k][c4 * 4]     = lo;
        *(dvec2*)&Bs[k][c4 * 4 + 2] = hi;
      }
    }
    __syncthreads();
#pragma unroll
    for (int kk = 0; kk < 16; kk++) {
      const dvec2 a01 = *(const dvec2*)&As[kk][ty * 4];
      const dvec2 a23 = *(const dvec2*)&As[kk][ty * 4 + 2];
      const dvec2 b01 = *(const dvec2*)&Bs[kk][tx * 8];
      const dvec2 b23 = *(const dvec2*)&Bs[kk][tx * 8 + 2];
      const dvec2 b45 = *(const dvec2*)&Bs[kk][tx * 8 + 4];
      const dvec2 b67 = *(const dvec2*)&Bs[kk][tx * 8 + 6];
      double a[4], b[8];
      a[0] = a01[0]; a[1] = a01[1]; a[2] = a23[0]; a[3] = a23[1];
      b[0] = b01[0]; b[1] = b01[1]; b[2] = b23[0]; b[3] = b23[1];
      b[4] = b45[0]; b[5] = b45[1]; b[6] = b67[0]; b[7] = b67[1];
#pragma unroll
      for (int i = 0; i < 4; i++)
#pragma unroll
        for (int j = 0; j < 8; j++)
          acc[i][j] = fma(a[i], b[j], acc[i][j]);
    }
    __syncthreads();
  }

#pragma unroll
  for (int i = 0; i < 4; i++) {
    const int m = m0 + ty * 4 + i;
#pragma unroll
    for (int j = 0; j < 8; j++) {
      const int c = jw + tx * 8 + j;
      const double v = acc[i][j] + (double)bp[c];
      const size_t off = (size_t)m * DK_ + c;
      if (isQ) {
        Qd[off] = v;
        if (Qbf) Qbf[off] = f32_to_bf16_rn((float)v);
      } else {
        Kd[off] = v;
        if (Kbf) Kbf[off] = f32_to_bf16_rn((float)v);
      }
    }
  }
}

// --------------------------------------------------------------------------
// Kernel 2a: scores via bf16 MFMA 16x16x32 (candidate precision only).
// --------------------------------------------------------------------------
__global__ __launch_bounds__(256) void score_bf16_kernel(
    const ushort_t* __restrict__ Qb, const ushort_t* __restrict__ Kb,
    float* __restrict__ out)
{
  __shared__ ushort_t Asl[128 * 40];
  __shared__ ushort_t Bsl[128 * 40];
  const int tid = threadIdx.x;
  const int b  = blockIdx.z;
  const int q0 = blockIdx.y * 128;
  const int m0 = blockIdx.x * 128;
  const int w = tid >> 6, lane = tid & 63;
  const int wq = (w >> 1) * 64, wm = (w & 1) * 64;
  const int rsel = lane & 15, ksel = (lane >> 4) * 8;

  avec4 acc[4][4];
#pragma unroll
  for (int i = 0; i < 4; i++)
#pragma unroll
    for (int j = 0; j < 4; j++) acc[i][j] = (avec4)(0.f);

  for (int k0 = 0; k0 < DK_; k0 += 32) {
#pragma unroll
    for (int cc = 0; cc < 2; cc++) {
      const int c = tid + cc * 256;
      const int r = c >> 2, part = c & 3;
      const ivec4 va = *(const ivec4*)&Qb[((size_t)b * N_ + q0 + r) * DK_ + k0 + part * 8];
      const ivec4 vb = *(const ivec4*)&Kb[((size_t)b * N_ + m0 + r) * DK_ + k0 + part * 8];
      *(ivec4*)&Asl[r * 40 + part * 8] = va;
      *(ivec4*)&Bsl[r * 40 + part * 8] = vb;
    }
    __syncthreads();
    bvec8 aF[4], bF[4];
#pragma unroll
    for (int mi = 0; mi < 4; mi++)
      aF[mi] = *(const bvec8*)&Asl[(wq + mi * 16 + rsel) * 40 + ksel];
#pragma unroll
    for (int nj = 0; nj < 4; nj++)
      bF[nj] = *(const bvec8*)&Bsl[(wm + nj * 16 + rsel) * 40 + ksel];
#pragma unroll
    for (int mi = 0; mi < 4; mi++)
#pragma unroll
      for (int nj = 0; nj < 4; nj++)
        acc[mi][nj] = __builtin_amdgcn_mfma_f32_16x16x32_bf16(
            aF[mi], bF[nj], acc[mi][nj], 0, 0, 0);
    __syncthreads();
  }

#pragma unroll
  for (int mi = 0; mi < 4; mi++)
#pragma unroll
    for (int nj = 0; nj < 4; nj++)
#pragma unroll
      for (int r = 0; r < 4; r++) {
        const int row = q0 + wq + mi * 16 + (lane >> 4) * 4 + r;
        const int col = m0 + wm + nj * 16 + (lane & 15);
        out[((size_t)b * N_ + row) * N_ + col] = acc[mi][nj][r] * 0.0625f;
      }
}

// --------------------------------------------------------------------------
// Kernel 2b (fallback if ws too small for bf16 copies): f32 scores from f64.
// --------------------------------------------------------------------------
__global__ __launch_bounds__(256) void score_f64_kernel(
    const double* __restrict__ Qd, const double* __restrict__ Kd,
    float* __restrict__ out)
{
  __shared__ float As[16][68];
  __shared__ float Bs[16][68];
  const int tid = threadIdx.x;
  const int tx = tid & 15, ty = tid >> 4;
  const int b  = blockIdx.z;
  const int q0 = blockIdx.y * 64;
  const int m0 = blockIdx.x * 64;
  const size_t rowbase = (size_t)b * N_;

  float acc[4][4];
#pragma unroll
  for (int i = 0; i < 4; i++)
#pragma unroll
    for (int j = 0; j < 4; j++) acc[i][j] = 0.f;

  for (int k0 = 0; k0 < DK_; k0 += 16) {
    const int mt = tid >> 4, kt = tid & 15;
#pragma unroll
    for (int p = 0; p < 4; p++) {
      const int m = mt + 16 * p;
      As[kt][m] = (float)Qd[(rowbase + q0 + m) * DK_ + k0 + kt];
      Bs[kt][m] = (float)Kd[(rowbase + m0 + m) * DK_ + k0 + kt];
    }
    __syncthreads();
#pragma unroll
    for (int kk = 0; kk < 16; kk++) {
      float a[4], bb[4];
#pragma unroll
      for (int i = 0; i < 4; i++) a[i] = As[kk][ty * 4 + i];
#pragma unroll
      for (int j = 0; j < 4; j++) bb[j] = Bs[kk][tx * 4 + j];
#pragma unroll
      for (int i = 0; i < 4; i++)
#pragma unroll
        for (int j = 0; j < 4; j++)
          acc[i][j] = fmaf(a[i], bb[j], acc[i][j]);
    }
    __syncthreads();
  }

#pragma unroll
  for (int i = 0; i < 4; i++) {
    const size_t r = (size_t)b * N_ + q0 + ty * 4 + i;
#pragma unroll
    for (int j = 0; j < 4; j++)
      out[r * N_ + m0 + tx * 4 + j] = acc[i][j] * 0.0625f;
  }
}

// --------------------------------------------------------------------------
// Kernel 3: per-row exact top-32 (radix select with margin + f64 rescore)
// and softmax. One block (256 threads) per row.
// --------------------------------------------------------------------------
__global__ __launch_bounds__(256) void topk_softmax_kernel(
    float* __restrict__ out, const double* __restrict__ Qd,
    const double* __restrict__ Kd, float margin)
{
  const int row = blockIdx.x;
  const int b   = row >> 11;
  const int tid = threadIdx.x;
  float* rowp = out + (size_t)row * N_;

  __shared__ float    s[N_];
  __shared__ double   qrow[DK_];
  __shared__ unsigned hist[256];
  __shared__ unsigned sfx[256];
  __shared__ int      cidx[128];
  __shared__ double   cval[128];
  __shared__ float    ceval[128];
  __shared__ int      ncand_s;
  __shared__ unsigned prefix_s;
  __shared__ int      want_s;
  __shared__ double   vmax_s;
  __shared__ float    esum_s;

  for (int i = tid; i < N_; i += 256) s[i] = rowp[i];
  qrow[tid] = Qd[(size_t)row * DK_ + tid];
  __syncthreads();

  // radix select: 32nd-largest noisy score
  unsigned prefix = 0;
  int want = TOPK;
  for (int pass = 0; pass < 4; pass++) {
    hist[tid] = 0;
    __syncthreads();
    const int shift_b = 24 - 8 * pass;
    for (int i = tid; i < N_; i += 256) {
      unsigned u = __float_as_uint(s[i]);
      u = (u & 0x80000000u) ? ~u : (u | 0x80000000u);
      const bool ok = (pass == 0) || ((u >> (shift_b + 8)) == prefix);
      if (ok) atomicAdd(&hist[(u >> shift_b) & 255u], 1u);
    }
    __syncthreads();
    sfx[tid] = hist[tid];
    __syncthreads();
    for (int st = 1; st < 256; st <<= 1) {
      const unsigned add = (tid + st < 256) ? sfx[tid + st] : 0u;
      __syncthreads();
      sfx[tid] += add;
      __syncthreads();
    }
    const int gt = (int)(sfx[tid] - hist[tid]);
    if (gt < want && (int)sfx[tid] >= want) {
      prefix_s = (prefix << 8) | (unsigned)tid;
      want_s = want - gt;
    }
    __syncthreads();
    prefix = prefix_s;
    want = want_s;
    __syncthreads();
  }
  const unsigned su = prefix;
  const unsigned uu = (su & 0x80000000u) ? (su ^ 0x80000000u) : ~su;
  const float t32 = __uint_as_float(uu);
  const float cthr = t32 - margin;

  // gather candidates
  if (tid == 0) ncand_s = 0;
  __syncthreads();
  for (int i = tid; i < N_; i += 256) {
    if (s[i] >= cthr) {
      const int p = atomicAdd(&ncand_s, 1);
      if (p < 128) cidx[p] = i;
    }
  }
  __syncthreads();
  int nc = ncand_s;
  if (nc > 128) nc = 128;

  // f64 rescore (one wave per candidate)
  const int wid = tid >> 6, lane = tid & 63;
  for (int base = 0; base < nc; base += 4) {
    const int c = base + wid;
    if (c < nc) {
      const double* kp = Kd + ((size_t)b * N_ + cidx[c]) * DK_;
      double a = 0.0;
#pragma unroll
      for (int q = 0; q < 4; q++)
        a = fma(qrow[lane * 4 + q], kp[lane * 4 + q], a);
#pragma unroll
      for (int off = 32; off > 0; off >>= 1) a += __shfl_xor(a, off);
      if (lane == 0) cval[c] = a * 0.0625;
    }
  }
  __syncthreads();

  // exact top-32 among candidates (value desc, index asc)
  bool sel = false;
  double v = 0.0;
  int myidx = 0;
  if (tid < nc) {
    v = cval[tid];
    myidx = cidx[tid];
    int rank = 0;
    for (int j = 0; j < nc; j++) {
      const double vj = cval[j];
      rank += (vj > v) || (vj == v && cidx[j] < myidx);
    }
    sel = (rank < TOPK);
  }
  if (tid == 0) {
    double mx = cval[0];
    for (int j = 1; j < nc; j++) mx = cval[j] > mx ? cval[j] : mx;
    vmax_s = mx;
  }
  __syncthreads();
  const float ev = sel ? expf((float)(v - vmax_s)) : 0.f;
  if (tid < 128) ceval[tid] = ev;
  __syncthreads();
  if (tid == 0) {
    float ssum = 0.f;
    for (int j = 0; j < nc; j++) ssum += ceval[j];
    esum_s = ssum;
  }
  __syncthreads();

  for (int i = tid; i < N_; i += 256) s[i] = 0.f;
  __syncthreads();
  if (tid < nc && sel) s[myidx] = ev / esum_s;
  __syncthreads();
  for (int i = tid; i < N_; i += 256) rowp[i] = s[i];
}

// --------------------------------------------------------------------------
extern "C" void kernel_launch(void* const* d_in, const int* in_sizes, int n_in,
                              void* d_out, int out_size, void* d_ws,
                              size_t ws_size, hipStream_t stream)
{
  const float* X  = (const float*)d_in[0];
  const float* Wq = (const float*)d_in[1];
  const float* bq = (const float*)d_in[2];
  const float* Wk = (const float*)d_in[3];
  const float* bk = (const float*)d_in[4];
  float* out = (float*)d_out;

  const size_t qk = (size_t)M_ * DK_;
  const size_t f64_bytes = qk * sizeof(double) * 2;           // 67.1 MB
  const size_t bf_bytes  = qk * sizeof(ushort_t) * 2;         // 16.8 MB
  if (ws_size < f64_bytes) return;
  const bool bfpath = (ws_size >= f64_bytes + bf_bytes);

  double* Qd = (double*)d_ws;
  double* Kd = Qd + qk;
  ushort_t* Qbf = (ushort_t*)(Kd + qk);
  ushort_t* Kbf = Qbf + qk;

  dim3 blk(256);
  proj_kernel<<<dim3(4, 256), blk, 0, stream>>>(
      X, Wq, bq, Wk, bk, Qd, Kd, bfpath ? Qbf : (ushort_t*)nullptr,
      bfpath ? Kbf : (ushort_t*)nullptr);

  float margin;
  if (bfpath) {
    score_bf16_kernel<<<dim3(N_ / 128, N_ / 128, B_), blk, 0, stream>>>(Qbf, Kbf, out);
    margin = 8e-3f;
  } else {
    score_f64_kernel<<<dim3(N_ / 64, N_ / 64, B_), blk, 0, stream>>>(Qd, Kd, out);
    margin = 2.5e-4f;
  }

  topk_softmax_kernel<<<dim3(M_), blk, 0, stream>>>(out, Qd, Kd, margin);
}

// Round 5
// 668.510 us; speedup vs baseline: 1.3079x; 1.3079x over previous
//
#include <hip/hip_runtime.h>
#include <cstdint>
#include <cstddef>

#define B_   8
#define N_   2048
#define D_   1024
#define DK_  256
#define M_   (B_ * N_)   // 16384
#define TOPK 32

typedef unsigned short ushort_t;
typedef float  fvec4 __attribute__((ext_vector_type(4)));
typedef short  bvec8 __attribute__((ext_vector_type(8)));   // 8 bf16 (bits)
typedef float  avec4 __attribute__((ext_vector_type(4)));   // f32 MFMA acc
typedef int    ivec4 __attribute__((ext_vector_type(4)));   // 16B staging

__device__ inline ushort_t f32_to_bf16_rn(float f) {
  unsigned u = __float_as_uint(f);
  u += 0x7fffu + ((u >> 16) & 1u);     // RNE (no inf/nan in this data)
  return (ushort_t)(u >> 16);
}

// --------------------------------------------------------------------------
// Kernel 1: fused Q/K projection GEMM, f64 accumulation on the VALU.
// Tile 128(m) x 128(j), BK=16, 8x8 per thread. LDS in f32 (proven cheap),
// cvt f64 at fragment load (16 cvt per 64 dfma = 6% of issue).
// j covers [0,512): blocks x=0,1 -> Q, x=2,3 -> K.
// --------------------------------------------------------------------------
__global__ __launch_bounds__(256) void proj_kernel(
    const float* __restrict__ X, const float* __restrict__ Wq,
    const float* __restrict__ bq, const float* __restrict__ Wk,
    const float* __restrict__ bk, double* __restrict__ Qd,
    double* __restrict__ Kd, ushort_t* __restrict__ Qbf,
    ushort_t* __restrict__ Kbf)
{
  __shared__ float As[16][132];   // [k][m], pad to 132 (528B rows, 16B-aligned)
  __shared__ float Bs[16][132];   // [k][j]
  const int tid = threadIdx.x;
  const int tx = tid & 15;        // col-group (8 cols)
  const int ty = tid >> 4;        // row-group (8 rows)
  const int m0 = blockIdx.y * 128;
  const int j0 = blockIdx.x * 128;         // 0,128,256,384
  const bool isQ = (j0 < 256);
  const float* Wp = isQ ? Wq : Wk;
  const float* bp = isQ ? bq : bk;
  const int jw = isQ ? j0 : (j0 - 256);

  double acc[8][8];
#pragma unroll
  for (int i = 0; i < 8; i++)
#pragma unroll
    for (int j = 0; j < 8; j++) acc[i][j] = 0.0;

  for (int k0 = 0; k0 < D_; k0 += 16) {
    {  // A tile: 128 rows x 16 k -> transposed As[k][m]. 2 fvec4 per thread.
      const int r  = tid >> 2;          // 0..63
      const int k4 = (tid & 3) * 4;     // 0,4,8,12
#pragma unroll
      for (int p = 0; p < 2; p++) {
        const int m = r + 64 * p;
        const fvec4 v = *(const fvec4*)&X[(size_t)(m0 + m) * D_ + k0 + k4];
#pragma unroll
        for (int c = 0; c < 4; c++) As[k4 + c][m] = v[c];
      }
    }
    {  // B tile: 16 k x 128 j, straight copy. 2 fvec4 per thread.
      const int k  = tid >> 4;          // 0..15
      const int j8 = (tid & 15) * 8;    // 0..120
      const fvec4 v0 = *(const fvec4*)&Wp[(size_t)(k0 + k) * DK_ + jw + j8];
      const fvec4 v1 = *(const fvec4*)&Wp[(size_t)(k0 + k) * DK_ + jw + j8 + 4];
      *(fvec4*)&Bs[k][j8]     = v0;
      *(fvec4*)&Bs[k][j8 + 4] = v1;
    }
    __syncthreads();
#pragma unroll
    for (int kk = 0; kk < 16; kk++) {
      const fvec4 a0 = *(const fvec4*)&As[kk][ty * 8];
      const fvec4 a1 = *(const fvec4*)&As[kk][ty * 8 + 4];
      const fvec4 b0 = *(const fvec4*)&Bs[kk][tx * 8];
      const fvec4 b1 = *(const fvec4*)&Bs[kk][tx * 8 + 4];
      double a[8], b[8];
#pragma unroll
      for (int i = 0; i < 4; i++) {
        a[i] = (double)a0[i]; a[i + 4] = (double)a1[i];
        b[i] = (double)b0[i]; b[i + 4] = (double)b1[i];
      }
#pragma unroll
      for (int i = 0; i < 8; i++)
#pragma unroll
        for (int j = 0; j < 8; j++)
          acc[i][j] = fma(a[i], b[j], acc[i][j]);
    }
    __syncthreads();
  }

#pragma unroll
  for (int i = 0; i < 8; i++) {
    const int m = m0 + ty * 8 + i;
#pragma unroll
    for (int j = 0; j < 8; j++) {
      const int c = jw + tx * 8 + j;
      const double v = acc[i][j] + (double)bp[c];
      const size_t off = (size_t)m * DK_ + c;
      if (isQ) {
        Qd[off] = v;
        if (Qbf) Qbf[off] = f32_to_bf16_rn((float)v);
      } else {
        Kd[off] = v;
        if (Kbf) Kbf[off] = f32_to_bf16_rn((float)v);
      }
    }
  }
}

// --------------------------------------------------------------------------
// Kernel 2a: scores via bf16 MFMA 16x16x32 (candidate precision only).
// --------------------------------------------------------------------------
__global__ __launch_bounds__(256) void score_bf16_kernel(
    const ushort_t* __restrict__ Qb, const ushort_t* __restrict__ Kb,
    float* __restrict__ out)
{
  __shared__ ushort_t Asl[128 * 40];
  __shared__ ushort_t Bsl[128 * 40];
  const int tid = threadIdx.x;
  const int b  = blockIdx.z;
  const int q0 = blockIdx.y * 128;
  const int m0 = blockIdx.x * 128;
  const int w = tid >> 6, lane = tid & 63;
  const int wq = (w >> 1) * 64, wm = (w & 1) * 64;
  const int rsel = lane & 15, ksel = (lane >> 4) * 8;

  avec4 acc[4][4];
#pragma unroll
  for (int i = 0; i < 4; i++)
#pragma unroll
    for (int j = 0; j < 4; j++) acc[i][j] = (avec4)(0.f);

  for (int k0 = 0; k0 < DK_; k0 += 32) {
#pragma unroll
    for (int cc = 0; cc < 2; cc++) {
      const int c = tid + cc * 256;
      const int r = c >> 2, part = c & 3;
      const ivec4 va = *(const ivec4*)&Qb[((size_t)b * N_ + q0 + r) * DK_ + k0 + part * 8];
      const ivec4 vb = *(const ivec4*)&Kb[((size_t)b * N_ + m0 + r) * DK_ + k0 + part * 8];
      *(ivec4*)&Asl[r * 40 + part * 8] = va;
      *(ivec4*)&Bsl[r * 40 + part * 8] = vb;
    }
    __syncthreads();
    bvec8 aF[4], bF[4];
#pragma unroll
    for (int mi = 0; mi < 4; mi++)
      aF[mi] = *(const bvec8*)&Asl[(wq + mi * 16 + rsel) * 40 + ksel];
#pragma unroll
    for (int nj = 0; nj < 4; nj++)
      bF[nj] = *(const bvec8*)&Bsl[(wm + nj * 16 + rsel) * 40 + ksel];
#pragma unroll
    for (int mi = 0; mi < 4; mi++)
#pragma unroll
      for (int nj = 0; nj < 4; nj++)
        acc[mi][nj] = __builtin_amdgcn_mfma_f32_16x16x32_bf16(
            aF[mi], bF[nj], acc[mi][nj], 0, 0, 0);
    __syncthreads();
  }

#pragma unroll
  for (int mi = 0; mi < 4; mi++)
#pragma unroll
    for (int nj = 0; nj < 4; nj++)
#pragma unroll
      for (int r = 0; r < 4; r++) {
        const int row = q0 + wq + mi * 16 + (lane >> 4) * 4 + r;
        const int col = m0 + wm + nj * 16 + (lane & 15);
        out[((size_t)b * N_ + row) * N_ + col] = acc[mi][nj][r] * 0.0625f;
      }
}

// --------------------------------------------------------------------------
// Kernel 2b (fallback if ws too small for bf16 copies): f32 scores from f64.
// --------------------------------------------------------------------------
__global__ __launch_bounds__(256) void score_f64_kernel(
    const double* __restrict__ Qd, const double* __restrict__ Kd,
    float* __restrict__ out)
{
  __shared__ float As[16][68];
  __shared__ float Bs[16][68];
  const int tid = threadIdx.x;
  const int tx = tid & 15, ty = tid >> 4;
  const int b  = blockIdx.z;
  const int q0 = blockIdx.y * 64;
  const int m0 = blockIdx.x * 64;
  const size_t rowbase = (size_t)b * N_;

  float acc[4][4];
#pragma unroll
  for (int i = 0; i < 4; i++)
#pragma unroll
    for (int j = 0; j < 4; j++) acc[i][j] = 0.f;

  for (int k0 = 0; k0 < DK_; k0 += 16) {
    const int mt = tid >> 4, kt = tid & 15;
#pragma unroll
    for (int p = 0; p < 4; p++) {
      const int m = mt + 16 * p;
      As[kt][m] = (float)Qd[(rowbase + q0 + m) * DK_ + k0 + kt];
      Bs[kt][m] = (float)Kd[(rowbase + m0 + m) * DK_ + k0 + kt];
    }
    __syncthreads();
#pragma unroll
    for (int kk = 0; kk < 16; kk++) {
      float a[4], bb[4];
#pragma unroll
      for (int i = 0; i < 4; i++) a[i] = As[kk][ty * 4 + i];
#pragma unroll
      for (int j = 0; j < 4; j++) bb[j] = Bs[kk][tx * 4 + j];
#pragma unroll
      for (int i = 0; i < 4; i++)
#pragma unroll
        for (int j = 0; j < 4; j++)
          acc[i][j] = fmaf(a[i], bb[j], acc[i][j]);
    }
    __syncthreads();
  }

#pragma unroll
  for (int i = 0; i < 4; i++) {
    const size_t r = (size_t)b * N_ + q0 + ty * 4 + i;
#pragma unroll
    for (int j = 0; j < 4; j++)
      out[r * N_ + m0 + tx * 4 + j] = acc[i][j] * 0.0625f;
  }
}

// --------------------------------------------------------------------------
// Kernel 3: per-row exact top-32 (radix select with margin + f64 rescore)
// and softmax. One block (256 threads) per row.
// --------------------------------------------------------------------------
__global__ __launch_bounds__(256) void topk_softmax_kernel(
    float* __restrict__ out, const double* __restrict__ Qd,
    const double* __restrict__ Kd, float margin)
{
  const int row = blockIdx.x;
  const int b   = row >> 11;
  const int tid = threadIdx.x;
  float* rowp = out + (size_t)row * N_;

  __shared__ float    s[N_];
  __shared__ double   qrow[DK_];
  __shared__ unsigned hist[256];
  __shared__ unsigned sfx[256];
  __shared__ int      cidx[128];
  __shared__ double   cval[128];
  __shared__ float    ceval[128];
  __shared__ int      ncand_s;
  __shared__ unsigned prefix_s;
  __shared__ int      want_s;
  __shared__ double   vmax_s;
  __shared__ float    esum_s;

  for (int i = tid; i < N_; i += 256) s[i] = rowp[i];
  qrow[tid] = Qd[(size_t)row * DK_ + tid];
  __syncthreads();

  // radix select: 32nd-largest noisy score
  unsigned prefix = 0;
  int want = TOPK;
  for (int pass = 0; pass < 4; pass++) {
    hist[tid] = 0;
    __syncthreads();
    const int shift_b = 24 - 8 * pass;
    for (int i = tid; i < N_; i += 256) {
      unsigned u = __float_as_uint(s[i]);
      u = (u & 0x80000000u) ? ~u : (u | 0x80000000u);
      const bool ok = (pass == 0) || ((u >> (shift_b + 8)) == prefix);
      if (ok) atomicAdd(&hist[(u >> shift_b) & 255u], 1u);
    }
    __syncthreads();
    sfx[tid] = hist[tid];
    __syncthreads();
    for (int st = 1; st < 256; st <<= 1) {
      const unsigned add = (tid + st < 256) ? sfx[tid + st] : 0u;
      __syncthreads();
      sfx[tid] += add;
      __syncthreads();
    }
    const int gt = (int)(sfx[tid] - hist[tid]);
    if (gt < want && (int)sfx[tid] >= want) {
      prefix_s = (prefix << 8) | (unsigned)tid;
      want_s = want - gt;
    }
    __syncthreads();
    prefix = prefix_s;
    want = want_s;
    __syncthreads();
  }
  const unsigned su = prefix;
  const unsigned uu = (su & 0x80000000u) ? (su ^ 0x80000000u) : ~su;
  const float t32 = __uint_as_float(uu);
  const float cthr = t32 - margin;

  // gather candidates
  if (tid == 0) ncand_s = 0;
  __syncthreads();
  for (int i = tid; i < N_; i += 256) {
    if (s[i] >= cthr) {
      const int p = atomicAdd(&ncand_s, 1);
      if (p < 128) cidx[p] = i;
    }
  }
  __syncthreads();
  int nc = ncand_s;
  if (nc > 128) nc = 128;

  // f64 rescore (one wave per candidate)
  const int wid = tid >> 6, lane = tid & 63;
  for (int base = 0; base < nc; base += 4) {
    const int c = base + wid;
    if (c < nc) {
      const double* kp = Kd + ((size_t)b * N_ + cidx[c]) * DK_;
      double a = 0.0;
#pragma unroll
      for (int q = 0; q < 4; q++)
        a = fma(qrow[lane * 4 + q], kp[lane * 4 + q], a);
#pragma unroll
      for (int off = 32; off > 0; off >>= 1) a += __shfl_xor(a, off);
      if (lane == 0) cval[c] = a * 0.0625;
    }
  }
  __syncthreads();

  // exact top-32 among candidates (value desc, index asc)
  bool sel = false;
  double v = 0.0;
  int myidx = 0;
  if (tid < nc) {
    v = cval[tid];
    myidx = cidx[tid];
    int rank = 0;
    for (int j = 0; j < nc; j++) {
      const double vj = cval[j];
      rank += (vj > v) || (vj == v && cidx[j] < myidx);
    }
    sel = (rank < TOPK);
  }
  if (tid == 0) {
    double mx = cval[0];
    for (int j = 1; j < nc; j++) mx = cval[j] > mx ? cval[j] : mx;
    vmax_s = mx;
  }
  __syncthreads();
  const float ev = sel ? expf((float)(v - vmax_s)) : 0.f;
  if (tid < 128) ceval[tid] = ev;
  __syncthreads();
  if (tid == 0) {
    float ssum = 0.f;
    for (int j = 0; j < nc; j++) ssum += ceval[j];
    esum_s = ssum;
  }
  __syncthreads();

  for (int i = tid; i < N_; i += 256) s[i] = 0.f;
  __syncthreads();
  if (tid < nc && sel) s[myidx] = ev / esum_s;
  __syncthreads();
  for (int i = tid; i < N_; i += 256) rowp[i] = s[i];
}

// --------------------------------------------------------------------------
extern "C" void kernel_launch(void* const* d_in, const int* in_sizes, int n_in,
                              void* d_out, int out_size, void* d_ws,
                              size_t ws_size, hipStream_t stream)
{
  const float* X  = (const float*)d_in[0];
  const float* Wq = (const float*)d_in[1];
  const float* bq = (const float*)d_in[2];
  const float* Wk = (const float*)d_in[3];
  const float* bk = (const float*)d_in[4];
  float* out = (float*)d_out;

  const size_t qk = (size_t)M_ * DK_;
  const size_t f64_bytes = qk * sizeof(double) * 2;           // 67.1 MB
  const size_t bf_bytes  = qk * sizeof(ushort_t) * 2;         // 16.8 MB
  if (ws_size < f64_bytes) return;
  const bool bfpath = (ws_size >= f64_bytes + bf_bytes);

  double* Qd = (double*)d_ws;
  double* Kd = Qd + qk;
  ushort_t* Qbf = (ushort_t*)(Kd + qk);
  ushort_t* Kbf = Qbf + qk;

  dim3 blk(256);
  proj_kernel<<<dim3(4, 128), blk, 0, stream>>>(
      X, Wq, bq, Wk, bk, Qd, Kd, bfpath ? Qbf : (ushort_t*)nullptr,
      bfpath ? Kbf : (ushort_t*)nullptr);

  float margin;
  if (bfpath) {
    score_bf16_kernel<<<dim3(N_ / 128, N_ / 128, B_), blk, 0, stream>>>(Qbf, Kbf, out);
    margin = 8e-3f;
  } else {
    score_f64_kernel<<<dim3(N_ / 64, N_ / 64, B_), blk, 0, stream>>>(Qd, Kd, out);
    margin = 2.5e-4f;
  }

  topk_softmax_kernel<<<dim3(M_), blk, 0, stream>>>(out, Qd, Kd, margin);
}